// Round 4
// baseline (563.026 us; speedup 1.0000x reference)
//
#include <hip/hip_runtime.h>
#include <hip/hip_bf16.h>

#define B_ 8
#define L_ 512
#define T_ 512
#define D_ 768
#define H_ 12
#define DH_ 64
#define SD_ 5
#define NSW_ 72   // H*(SD+1)
#define K2_ 1536  // split A:  [hi | lo]
#define K3_ 2304  // split W:  [hi | lo | hi]

typedef __attribute__((ext_vector_type(8))) short bf16x8;
typedef __attribute__((ext_vector_type(4))) float f32x4;
typedef unsigned short ushort_t;

__device__ __forceinline__ unsigned short f2bf(float x) {
    union { __hip_bfloat16 h; unsigned short u; } cv;
    cv.h = __float2bfloat16(x);
    return cv.u;
}
__device__ __forceinline__ float bf2f(unsigned short u) {
    union { unsigned short u; __hip_bfloat16 h; } cv;
    cv.u = u;
    return __bfloat162float(cv.h);
}

__device__ __forceinline__ void gload_lds16(const void* g, void* l) {
    __builtin_amdgcn_global_load_lds((const __attribute__((address_space(1))) void*)g,
                                     (__attribute__((address_space(3))) void*)l,
                                     16, 0, 0);
}

// ---------------------------------------------------------------------------
__global__ __launch_bounds__(256) void zero_kernel(float4* __restrict__ p) {
    p[(size_t)blockIdx.x * 256 + threadIdx.x] = make_float4(0.f, 0.f, 0.f, 0.f);
}

// out[m][n] = bf[n]  (final GEMM then atomically accumulates on top)
__global__ __launch_bounds__(256) void bias_init(
    float4* __restrict__ out4, const float4* __restrict__ bf4)
{
    const size_t idx = (size_t)blockIdx.x * 256 + threadIdx.x;  // 786432 f4
    out4[idx] = bf4[idx % 192];
}

// ---------------------------------------------------------------------------
// Split fp32 activations -> A2 = [hi | lo] bf16, row-major [M][1536].
// ---------------------------------------------------------------------------
__global__ __launch_bounds__(256) void asplit_kernel(
    const float* __restrict__ q, const float* __restrict__ k, const float* __restrict__ v,
    short* __restrict__ q2, short* __restrict__ k2, short* __restrict__ v2)
{
    const int z = blockIdx.z;
    const float* A = (z == 0) ? q : (z == 1) ? k : v;
    short* O = (z == 0) ? q2 : (z == 1) ? k2 : v2;
    const int col = blockIdx.x * 256 + threadIdx.x;
    const int m   = blockIdx.y;
    if (col >= D_) return;
    const float a = A[(size_t)m * D_ + col];
    const unsigned short hi = f2bf(a);
    const unsigned short lo = f2bf(a - bf2f(hi));
    O[(size_t)m * K2_ + col]       = (short)hi;
    O[(size_t)m * K2_ + D_ + col]  = (short)lo;
}

// ---------------------------------------------------------------------------
// Transpose + split weights -> WT3 [Npad x 2304]: row n = [hi | lo | hi].
// ---------------------------------------------------------------------------
__global__ __launch_bounds__(256) void wsplit_kernel(
    const float* __restrict__ Wq, const float* __restrict__ Wk,
    const float* __restrict__ Wv, const float* __restrict__ Wl,
    const float* __restrict__ Wf,
    short* __restrict__ WqT3, short* __restrict__ WkT3, short* __restrict__ WvT3,
    short* __restrict__ WlT3, short* __restrict__ WfT3)
{
    const int z = blockIdx.z;
    const float* W; short* O; int Nw, Npad;
    if (z == 0)      { W = Wq; O = WqT3; Nw = D_;   Npad = 768; }
    else if (z == 1) { W = Wk; O = WkT3; Nw = D_;   Npad = 768; }
    else if (z == 2) { W = Wv; O = WvT3; Nw = D_;   Npad = 768; }
    else if (z == 3) { W = Wl; O = WlT3; Nw = NSW_; Npad = 128; }
    else             { W = Wf; O = WfT3; Nw = D_;   Npad = 768; }

    const int k0 = blockIdx.x * 64;
    const int n0 = blockIdx.y * 64;
    if (n0 >= Npad) return;

    __shared__ float sm[64][65];
    const int c  = threadIdx.x & 63;
    const int r4 = threadIdx.x >> 6;

#pragma unroll
    for (int i = 0; i < 16; i++) {
        const int r = i * 4 + r4;
        float val = 0.f;
        if (n0 + c < Nw) val = W[(size_t)(k0 + r) * Nw + n0 + c];
        sm[r][c] = val;
    }
    __syncthreads();

#pragma unroll
    for (int i = 0; i < 16; i++) {
        const int nl = i * 4 + r4;
        const int n  = n0 + nl;
        if (n >= Npad) continue;
        const float v = (n < Nw) ? sm[c][nl] : 0.f;
        const unsigned short hi = f2bf(v);
        const unsigned short lo = f2bf(v - bf2f(hi));
        const size_t rb = (size_t)n * K3_;
        O[rb + k0 + c]        = (short)hi;
        O[rb + 768 + k0 + c]  = (short)lo;
        O[rb + 1536 + k0 + c] = (short)hi;
    }
}

// ---------------------------------------------------------------------------
// Split-K=2 proj GEMM. z 0..5: g=z>>1 (0=q,1=k,2=v), part=z&1. z==6: Wl,
// part=blockIdx.x (only x<2 work). Accumulates fp32 via HW atomics into
// Cp[g][4096][768] / Cpsw[4096][72] (zeroed beforehand; 2-term fp32 atomic
// accumulation is order-commutative -> deterministic).
// ---------------------------------------------------------------------------
__global__ __launch_bounds__(256, 4) void proj_gemm(
    const short* __restrict__ q2, const short* __restrict__ k2, const short* __restrict__ v2,
    const short* __restrict__ WqT3, const short* __restrict__ WkT3,
    const short* __restrict__ WvT3, const short* __restrict__ WlT3,
    float* __restrict__ Cp, float* __restrict__ Cpsw)
{
    const int z = blockIdx.z;
    int g, part, bx = blockIdx.x;
    if (z < 6) { g = z >> 1; part = z & 1; }
    else       { if (bx >= 2) return; g = 3; part = bx; bx = 0; }

    const short* A2  = (g == 1) ? k2 : (g == 2) ? v2 : q2;
    const short* WT3 = (g == 0) ? WqT3 : (g == 1) ? WkT3 : (g == 2) ? WvT3 : WlT3;
    float* C   = (g < 3) ? (Cp + (size_t)g * 4096 * 768) : Cpsw;
    const int Ncols = (g < 3) ? 768 : NSW_;

    const int m0 = blockIdx.y * 128;
    const int n0 = bx * 128;

    __shared__ __align__(16) short As[128 * 32];
    __shared__ __align__(16) short Bs[128 * 32];

    const int tid  = threadIdx.x;
    const int lane = tid & 63;
    const int wv_  = tid >> 6;
    const int wm   = (wv_ & 1) << 6;
    const int wn   = (wv_ >> 1) << 6;
    const int l15  = lane & 15;
    const int quad = lane >> 4;

    f32x4 acc[4][4] = {};

    const int sa  = tid;
    const int sb  = tid + 256;
    const int ra  = sa >> 2, ka = (sa & 3) << 3;
    const int rb  = sb >> 2, kb8 = (sb & 3) << 3;

    const int kbeg = part * 1152;
    for (int kb = kbeg; kb < kbeg + 1152; kb += 32) {
        const int akb = (kb < 768) ? kb : kb - 768;
        __syncthreads();
        gload_lds16(A2  + (size_t)(m0 + ra) * K2_ + akb + ka,  &As[sa << 3]);
        gload_lds16(A2  + (size_t)(m0 + rb) * K2_ + akb + kb8, &As[sb << 3]);
        gload_lds16(WT3 + (size_t)(n0 + ra) * K3_ + kb  + ka,  &Bs[sa << 3]);
        gload_lds16(WT3 + (size_t)(n0 + rb) * K3_ + kb  + kb8, &Bs[sb << 3]);
        __syncthreads();

        bf16x8 af[4], bfr[4];
#pragma unroll
        for (int t = 0; t < 4; t++) {
            af[t]  = *(const bf16x8*)&As[(wm + t * 16 + l15) * 32 + quad * 8];
            bfr[t] = *(const bf16x8*)&Bs[(wn + t * 16 + l15) * 32 + quad * 8];
        }
#pragma unroll
        for (int mt = 0; mt < 4; mt++)
#pragma unroll
            for (int nt = 0; nt < 4; nt++)
                acc[mt][nt] = __builtin_amdgcn_mfma_f32_16x16x32_bf16(
                    af[mt], bfr[nt], acc[mt][nt], 0, 0, 0);
    }

#pragma unroll
    for (int nt = 0; nt < 4; nt++) {
        const int col = n0 + wn + nt * 16 + l15;
        if (col >= Ncols) continue;
#pragma unroll
        for (int mt = 0; mt < 4; mt++) {
            const int rowb = m0 + wm + mt * 16 + quad * 4;
#pragma unroll
            for (int r = 0; r < 4; r++)
                unsafeAtomicAdd(&C[(size_t)(rowb + r) * Ncols + col], acc[mt][nt][r]);
        }
    }
}

// ---------------------------------------------------------------------------
// Split-K=4 final GEMM: out += outp2 (x) WfT3 (bias pre-initialized).
// ---------------------------------------------------------------------------
__global__ __launch_bounds__(256, 4) void final_gemm(
    const short* __restrict__ A2, const short* __restrict__ WT3,
    float* __restrict__ out)
{
    const int part = blockIdx.z;
    const int m0 = blockIdx.y * 128;
    const int n0 = blockIdx.x * 128;

    __shared__ __align__(16) short As[128 * 32];
    __shared__ __align__(16) short Bs[128 * 32];

    const int tid  = threadIdx.x;
    const int lane = tid & 63;
    const int wv_  = tid >> 6;
    const int wm   = (wv_ & 1) << 6;
    const int wn   = (wv_ >> 1) << 6;
    const int l15  = lane & 15;
    const int quad = lane >> 4;

    f32x4 acc[4][4] = {};

    const int sa  = tid;
    const int sb  = tid + 256;
    const int ra  = sa >> 2, ka = (sa & 3) << 3;
    const int rb  = sb >> 2, kb8 = (sb & 3) << 3;

    const int kbeg = part * 576;
    for (int kb = kbeg; kb < kbeg + 576; kb += 32) {
        const int akb = (kb < 768) ? kb : kb - 768;
        __syncthreads();
        gload_lds16(A2  + (size_t)(m0 + ra) * K2_ + akb + ka,  &As[sa << 3]);
        gload_lds16(A2  + (size_t)(m0 + rb) * K2_ + akb + kb8, &As[sb << 3]);
        gload_lds16(WT3 + (size_t)(n0 + ra) * K3_ + kb  + ka,  &Bs[sa << 3]);
        gload_lds16(WT3 + (size_t)(n0 + rb) * K3_ + kb  + kb8, &Bs[sb << 3]);
        __syncthreads();

        bf16x8 af[4], bfr[4];
#pragma unroll
        for (int t = 0; t < 4; t++) {
            af[t]  = *(const bf16x8*)&As[(wm + t * 16 + l15) * 32 + quad * 8];
            bfr[t] = *(const bf16x8*)&Bs[(wn + t * 16 + l15) * 32 + quad * 8];
        }
#pragma unroll
        for (int mt = 0; mt < 4; mt++)
#pragma unroll
            for (int nt = 0; nt < 4; nt++)
                acc[mt][nt] = __builtin_amdgcn_mfma_f32_16x16x32_bf16(
                    af[mt], bfr[nt], acc[mt][nt], 0, 0, 0);
    }

#pragma unroll
    for (int nt = 0; nt < 4; nt++) {
        const int col = n0 + wn + nt * 16 + l15;
#pragma unroll
        for (int mt = 0; mt < 4; mt++) {
            const int rowb = m0 + wm + mt * 16 + quad * 4;
#pragma unroll
            for (int r = 0; r < 4; r++)
                unsafeAtomicAdd(&out[(size_t)(rowb + r) * D_ + col], acc[mt][nt][r]);
        }
    }
}

// ---------------------------------------------------------------------------
// convert_qk: qs2a/ks2a [h][b][l][hi64|lo64] = split(Cp[g] + bias_g)
// ---------------------------------------------------------------------------
__global__ __launch_bounds__(256) void convert_qk(
    const float* __restrict__ Cp, const float* __restrict__ bq,
    const float* __restrict__ bk,
    ushort_t* __restrict__ qs2a, ushort_t* __restrict__ ks2a)
{
    const int g = blockIdx.z;
    const float* src  = Cp + (size_t)g * 4096 * 768;
    const float* bias = g ? bk : bq;
    ushort_t* dst = g ? ks2a : qs2a;
    const int r0 = blockIdx.x * 8;

#pragma unroll
    for (int j = 0; j < 6; j++) {
        const int idx = threadIdx.x + 256 * j;       // 0..1535
        const int row = r0 + idx / 192;
        const int c4  = (idx % 192) * 4;
        float4 x = *(const float4*)&src[(size_t)row * 768 + c4];
        const float4 b4 = *(const float4*)&bias[c4];
        x.x += b4.x; x.y += b4.y; x.z += b4.z; x.w += b4.w;
        const int hh = c4 >> 6, dd = c4 & 63;
        const int bb = row >> 9, ll = row & 511;
        const size_t base = (((size_t)hh * B_ + bb) * 512 + ll) * 128 + dd;
        ushort_t hi[4], lo[4];
        const float xv[4] = {x.x, x.y, x.z, x.w};
#pragma unroll
        for (int u = 0; u < 4; u++) {
            hi[u] = f2bf(xv[u]);
            lo[u] = f2bf(xv[u] - bf2f(hi[u]));
        }
        *(ushort4*)&dst[base]      = *(ushort4*)hi;
        *(ushort4*)&dst[base + 64] = *(ushort4*)lo;
    }
}

// ---------------------------------------------------------------------------
// convert_v: vt2 [h][b][c(hi) / 64+c(lo)][t] = transpose(split(Cp[2] + bv))
// ---------------------------------------------------------------------------
__global__ __launch_bounds__(256) void convert_v(
    const float* __restrict__ Cp, const float* __restrict__ bv,
    ushort_t* __restrict__ vt2)
{
    const int t0 = blockIdx.x * 64;
    const int b  = blockIdx.y;
    const int h  = blockIdx.z;
    const float* src = Cp + (size_t)2 * 4096 * 768;

    __shared__ float sm[64][65];
    const int tid = threadIdx.x;
    {
        const int r = tid >> 2, cseg = (tid & 3) * 16;
        const size_t rowb = (size_t)(b * 512 + t0 + r) * 768 + h * 64 + cseg;
#pragma unroll
        for (int u = 0; u < 4; u++) {
            float4 x = *(const float4*)&src[rowb + u * 4];
            sm[r][cseg + u * 4 + 0] = x.x;
            sm[r][cseg + u * 4 + 1] = x.y;
            sm[r][cseg + u * 4 + 2] = x.z;
            sm[r][cseg + u * 4 + 3] = x.w;
        }
    }
    __syncthreads();
    {
        const int c = tid >> 2, seg = (tid & 3) * 16;
        const float bvv = bv[h * 64 + c];
        ushort_t hib[16], lob[16];
#pragma unroll
        for (int i = 0; i < 16; i++) {
            const float val = sm[seg + i][c] + bvv;
            hib[i] = f2bf(val);
            lob[i] = f2bf(val - bf2f(hib[i]));
        }
        const size_t bh = (((size_t)h * B_ + b) * 128 + c) * 512 + t0 + seg;
        const size_t bl = bh + (size_t)64 * 512;
#pragma unroll
        for (int u = 0; u < 4; u++) {
            *(ushort4*)&vt2[bh + u * 4] = *(ushort4*)&hib[u * 4];
            *(ushort4*)&vt2[bl + u * 4] = *(ushort4*)&lob[u * 4];
        }
    }
}

__global__ __launch_bounds__(256) void convert_sw(
    const float* __restrict__ Cpsw, const float* __restrict__ bl,
    float* __restrict__ swv)
{
    const int idx = blockIdx.x * 256 + threadIdx.x;   // < 294912
    swv[idx] = Cpsw[idx] + bl[idx % NSW_];
}

// ---------------------------------------------------------------------------
// sig16[h][b][l][t] = mask ? 0 : max(sigmoid(bias_h + w_h · ploc[b,l,t,:]), 1e-6)
// ---------------------------------------------------------------------------
__global__ __launch_bounds__(256) void sig_kernel(
    const float* __restrict__ ploc, const float* __restrict__ swv,
    const int* __restrict__ maskp, _Float16* __restrict__ sig16)
{
    const int b = blockIdx.y;
    const int l = blockIdx.x;
    const int tid = threadIdx.x;

    __shared__ float pls[512 * 5];
    __shared__ float sws[72];
    __shared__ int   msk[512];

    const float* src = ploc + (size_t)(b * 512 + l) * 512 * 5;
    for (int i = tid; i < 640; i += 256)
        *(float4*)&pls[i * 4] = *(const float4*)(src + i * 4);
    if (tid < 72) sws[tid] = swv[(size_t)(b * 512 + l) * NSW_ + tid];
    for (int i = tid; i < 512; i += 256) msk[i] = maskp[b * 512 + i];
    __syncthreads();

    for (int e = tid; e < H_ * 512; e += 256) {
        const int t  = e & 511;
        const int hh = e >> 9;
        float s = sws[hh * 6];
#pragma unroll
        for (int d = 0; d < SD_; d++) s += sws[hh * 6 + 1 + d] * pls[t * 5 + d];
        const float sig = msk[t] ? 0.f : fmaxf(1.f / (1.f + __expf(-s)), 1e-6f);
        sig16[(((size_t)hh * B_ + b) * 512 + l) * 512 + t] = (_Float16)sig;
    }
}

// ---------------------------------------------------------------------------
// MFMA attention with Q fragments in registers and fused normalization.
// Block = (h, b, 64-l-tile); 64-wide t-tiles. Writes normalized fused (via
// self-owned L2-hot reread) and normalized PV output (split hi/lo) to outp2.
// ---------------------------------------------------------------------------
__global__ __launch_bounds__(256, 3) void attn_kernel(
    const ushort_t* __restrict__ qs2, const ushort_t* __restrict__ ks2,
    const ushort_t* __restrict__ vt2, const _Float16* __restrict__ sig16,
    float* __restrict__ fused, ushort_t* __restrict__ outp2)
{
    const int h  = blockIdx.z;
    const int b  = blockIdx.y;
    const int l0 = blockIdx.x << 6;
    const int hb = h * B_ + b;
    const int tid  = threadIdx.x;
    const int lane = tid & 63;
    const int wv   = tid >> 6;
    const int l15  = lane & 15;
    const int quad = lane >> 4;

    __shared__ __align__(16) ushort_t ks[64 * 128];
    __shared__ __align__(16) ushort_t vts[128 * 64];
    __shared__ __align__(16) ushort_t ps[64 * 136];   // [l][hi64 | lo64 | pad]
    __shared__ float ssb[4 * 64];
    __shared__ float ssum[64];

    // Q fragments: loop-invariant, straight from global into registers.
    bf16x8 aq[4][4];
    {
        const size_t qbase = ((size_t)hb * 512 + l0) * 128;
#pragma unroll
        for (int mt = 0; mt < 4; mt++) {
            const size_t rb = qbase + (size_t)(mt * 16 + l15) * 128;
#pragma unroll
            for (int c = 0; c < 4; c++)
                aq[mt][c] = *(const bf16x8*)(qs2 + rb + (c * 4 + quad) * 8);
        }
    }

    float pacc = 0.f;
    f32x4 accpv[4] = {};

    for (int t0 = 0; t0 < T_; t0 += 64) {
        __syncthreads();
        {
            const size_t kbase = ((size_t)hb * 512 + t0) * 128;
#pragma unroll
            for (int j = 0; j < 4; j++) {
                const int i = tid + 256 * j;
                const int r = i >> 4, c = i & 15, gc = c ^ (r & 7);
                gload_lds16(ks2 + kbase + r * 128 + gc * 8, &ks[i * 8]);
            }
            const size_t vbase = (size_t)hb * 128 * 512;
#pragma unroll
            for (int j = 0; j < 4; j++) {
                const int i = tid + 256 * j;
                const int r = i >> 3, c = i & 7, gc = c ^ (r & 7);
                gload_lds16(vt2 + vbase + (size_t)r * 512 + t0 + gc * 8, &vts[i * 8]);
            }
        }
        __syncthreads();

        // sig values for this wave's 64x16 S-slice
        float sigv[4][4];
        {
            const _Float16* sgp = sig16 + (((size_t)hb * 512 + l0) * 512) + t0 + wv * 16 + l15;
#pragma unroll
            for (int mt = 0; mt < 4; mt++)
#pragma unroll
                for (int r2 = 0; r2 < 4; r2++)
                    sigv[mt][r2] = (float)sgp[(size_t)(mt * 16 + quad * 4 + r2) * 512];
        }

        // ---- QK ----
        f32x4 acq[4] = {};
        {
            const int trow = wv * 16 + l15;
            const int tsw  = trow & 7;
            const bf16x8 bk0 = *(const bf16x8*)&ks[trow * 128 + ((0  + quad) ^ tsw) * 8];
            const bf16x8 bk1 = *(const bf16x8*)&ks[trow * 128 + ((4  + quad) ^ tsw) * 8];
            const bf16x8 bk2 = *(const bf16x8*)&ks[trow * 128 + ((8  + quad) ^ tsw) * 8];
            const bf16x8 bk3 = *(const bf16x8*)&ks[trow * 128 + ((12 + quad) ^ tsw) * 8];
#pragma unroll
            for (int mt = 0; mt < 4; mt++) {
                f32x4 a = acq[mt];
                a = __builtin_amdgcn_mfma_f32_16x16x32_bf16(aq[mt][0], bk0, a, 0, 0, 0);
                a = __builtin_amdgcn_mfma_f32_16x16x32_bf16(aq[mt][1], bk1, a, 0, 0, 0);
                a = __builtin_amdgcn_mfma_f32_16x16x32_bf16(aq[mt][0], bk2, a, 0, 0, 0);
                a = __builtin_amdgcn_mfma_f32_16x16x32_bf16(aq[mt][1], bk3, a, 0, 0, 0);
                a = __builtin_amdgcn_mfma_f32_16x16x32_bf16(aq[mt][2], bk0, a, 0, 0, 0);
                a = __builtin_amdgcn_mfma_f32_16x16x32_bf16(aq[mt][3], bk1, a, 0, 0, 0);
                acq[mt] = a;
            }
        }

        // ---- p = sig * exp(qk/8), split to LDS ----
        {
            const int tcol = wv * 16 + l15;
#pragma unroll
            for (int mt = 0; mt < 4; mt++)
#pragma unroll
                for (int r2 = 0; r2 < 4; r2++) {
                    const int lrow = mt * 16 + quad * 4 + r2;
                    const float p  = sigv[mt][r2] * __expf(acq[mt][r2] * 0.125f);
                    const ushort_t hi = f2bf(p);
                    const ushort_t lo = f2bf(p - bf2f(hi));
                    ps[lrow * 136 + tcol]      = hi;
                    ps[lrow * 136 + 64 + tcol] = lo;
                }
        }
        __syncthreads();

        // ---- unnormalized fused store (self-owned pattern) + row partials ----
        {
            const int row = tid >> 2, c4 = tid & 3;
            float vbuf[16];
            float s = 0.f;
#pragma unroll
            for (int jj = 0; jj < 16; jj++) {
                const int t = c4 * 16 + jj;
                const float pv = bf2f(ps[row * 136 + t]) + bf2f(ps[row * 136 + 64 + t]);
                vbuf[jj] = pv;
                s += pv;
            }
            pacc += s;
            float* dstf = fused + ((size_t)hb * 512 + l0 + row) * 512 + t0 + c4 * 16;
#pragma unroll
            for (int jj = 0; jj < 4; jj++)
                *(float4*)(dstf + jj * 4) = *(float4*)&vbuf[jj * 4];
        }

        // ---- PV ----
        {
            const int vrh = wv * 16 + l15;
            const int vrl = 64 + vrh;
            const int swh = vrh & 7, swl = vrl & 7;
            const bf16x8 bh0 = *(const bf16x8*)&vts[vrh * 64 + ((0 + quad) ^ swh) * 8];
            const bf16x8 bh1 = *(const bf16x8*)&vts[vrh * 64 + ((4 + quad) ^ swh) * 8];
            const bf16x8 bl0 = *(const bf16x8*)&vts[vrl * 64 + ((0 + quad) ^ swl) * 8];
            const bf16x8 bl1 = *(const bf16x8*)&vts[vrl * 64 + ((4 + quad) ^ swl) * 8];
#pragma unroll
            for (int mt = 0; mt < 4; mt++) {
                const int prow = mt * 16 + l15;
                const bf16x8 ph0 = *(const bf16x8*)&ps[prow * 136 + 0  + quad * 8];
                const bf16x8 ph1 = *(const bf16x8*)&ps[prow * 136 + 32 + quad * 8];
                const bf16x8 pl0 = *(const bf16x8*)&ps[prow * 136 + 64 + quad * 8];
                const bf16x8 pl1 = *(const bf16x8*)&ps[prow * 136 + 96 + quad * 8];
                f32x4 a = accpv[mt];
                a = __builtin_amdgcn_mfma_f32_16x16x32_bf16(ph0, bh0, a, 0, 0, 0);
                a = __builtin_amdgcn_mfma_f32_16x16x32_bf16(ph1, bh1, a, 0, 0, 0);
                a = __builtin_amdgcn_mfma_f32_16x16x32_bf16(ph0, bl0, a, 0, 0, 0);
                a = __builtin_amdgcn_mfma_f32_16x16x32_bf16(ph1, bl1, a, 0, 0, 0);
                a = __builtin_amdgcn_mfma_f32_16x16x32_bf16(pl0, bh0, a, 0, 0, 0);
                a = __builtin_amdgcn_mfma_f32_16x16x32_bf16(pl1, bh1, a, 0, 0, 0);
                accpv[mt] = a;
            }
        }
    }

    __syncthreads();
    ssb[(tid & 3) * 64 + (tid >> 2)] = pacc;
    __syncthreads();
    if (tid < 64) {
        ssum[tid] = ssb[tid] + ssb[64 + tid] + ssb[128 + tid] + ssb[192 + tid];
    }
    __syncthreads();

    // ---- fused normalization: rescale self-owned slab (L2-hot) ----
    {
        const int row = tid >> 2, c4 = tid & 3;
        const float inv = 1.f / ssum[row];
        float* frow = fused + ((size_t)hb * 512 + l0 + row) * 512 + c4 * 16;
        for (int t0 = 0; t0 < T_; t0 += 64) {
#pragma unroll
            for (int jj = 0; jj < 4; jj++) {
                float4 x = *(float4*)(frow + t0 + jj * 4);
                x.x *= inv; x.y *= inv; x.z *= inv; x.w *= inv;
                *(float4*)(frow + t0 + jj * 4) = x;
            }
        }
    }

    // ---- normalized PV output, split hi/lo for final GEMM ----
#pragma unroll
    for (int mt = 0; mt < 4; mt++)
#pragma unroll
        for (int r2 = 0; r2 < 4; r2++) {
            const int lrow = mt * 16 + quad * 4 + r2;
            const float val = accpv[mt][r2] / ssum[lrow];
            const ushort_t hi = f2bf(val);
            const ushort_t lo = f2bf(val - bf2f(hi));
            const size_t obase = ((size_t)(b * 512 + l0 + lrow)) * K2_ + h * 64 + wv * 16 + l15;
            outp2[obase]       = hi;
            outp2[obase + D_]  = lo;
        }
}

// ---------------------------------------------------------------------------
extern "C" void kernel_launch(void* const* d_in, const int* in_sizes, int n_in,
                              void* d_out, int out_size, void* d_ws, size_t ws_size,
                              hipStream_t stream) {
    const float* q    = (const float*)d_in[0];
    const float* k    = (const float*)d_in[1];
    const float* v    = (const float*)d_in[2];
    const float* ploc = (const float*)d_in[3];
    const int*   mask = (const int*)  d_in[4];
    const float* Wq   = (const float*)d_in[5];
    const float* bq   = (const float*)d_in[6];
    const float* Wk   = (const float*)d_in[7];
    const float* bk   = (const float*)d_in[8];
    const float* Wv   = (const float*)d_in[9];
    const float* bv   = (const float*)d_in[10];
    const float* Wl   = (const float*)d_in[11];
    const float* bl   = (const float*)d_in[12];
    const float* Wf   = (const float*)d_in[13];
    const float* bf   = (const float*)d_in[14];

    // Arena (byte offsets). Overlays exploit phase lifetimes:
    //  q2/k2/v2 (dead after proj_gemm) <- qs2a/ks2a/vt2
    //  WqT3 (dead after proj_gemm)     <- swv
    //  Cp/Cpsw (dead after converts)   <- sig16 / outp2
    char* base = (char*)d_ws;
    short*    q2    = (short*)(base + 0);             // 12,582,912
    short*    k2    = (short*)(base + 12582912);
    short*    v2    = (short*)(base + 25165824);
    short*    WqT3  = (short*)(base + 37748736);      //  3,538,944
    short*    WkT3  = (short*)(base + 41287680);
    short*    WvT3  = (short*)(base + 44826624);
    short*    WlT3  = (short*)(base + 48365568);      //    589,824
    short*    WfT3  = (short*)(base + 48955392);      //  3,538,944 (live -> final)
    float*    Cp    = (float*)(base + 52494336);      // 37,748,736 (3x 4096x768 f32)
    float*    Cpsw  = (float*)(base + 90243072);      //  1,179,648
    ushort_t* qs2a  = (ushort_t*)q2;                  // overlay
    ushort_t* ks2a  = (ushort_t*)k2;
    ushort_t* vt2   = (ushort_t*)v2;
    float*    swv   = (float*)WqT3;                   // overlay
    _Float16* sig16 = (_Float16*)(base + 52494336);   // 50,331,648 overlay over Cp+
    ushort_t* outp2 = (ushort_t*)(base + 102825984);  // 12,582,912 -> total 115,408,896

    float* out   = (float*)d_out;
    float* fused = out + (size_t)4096 * D_;

    zero_kernel<<<dim3(9504), 256, 0, stream>>>((float4*)Cp);   // Cp + Cpsw
    bias_init<<<dim3(3072), 256, 0, stream>>>((float4*)out, (const float4*)bf);

    asplit_kernel<<<dim3(3, 4096, 3), 256, 0, stream>>>(q, k, v, q2, k2, v2);
    wsplit_kernel<<<dim3(12, 12, 5), 256, 0, stream>>>(
        Wq, Wk, Wv, Wl, Wf, WqT3, WkT3, WvT3, WlT3, WfT3);

    proj_gemm<<<dim3(6, 32, 7), 256, 0, stream>>>(
        q2, k2, v2, WqT3, WkT3, WvT3, WlT3, Cp, Cpsw);

    convert_qk<<<dim3(512, 1, 2), 256, 0, stream>>>(Cp, bq, bk, qs2a, ks2a);
    convert_v<<<dim3(8, 8, 12), 256, 0, stream>>>(Cp, bv, vt2);
    convert_sw<<<dim3(1152), 256, 0, stream>>>(Cpsw, bl, swv);

    sig_kernel<<<dim3(512, 8), 256, 0, stream>>>(ploc, swv, mask, sig16);

    attn_kernel<<<dim3(8, 8, 12), 256, 0, stream>>>(
        qs2a, ks2a, vt2, sig16, fused, outp2);

    final_gemm<<<dim3(6, 32, 4), 256, 0, stream>>>((const short*)outp2, WfT3, out);
}

// Round 5
// 536.582 us; speedup vs baseline: 1.0493x; 1.0493x over previous
//
#include <hip/hip_runtime.h>
#include <hip/hip_bf16.h>

#define B_ 8
#define L_ 512
#define T_ 512
#define D_ 768
#define H_ 12
#define DH_ 64
#define SD_ 5
#define NSW_ 72   // H*(SD+1)
#define K2_ 1536  // split A:  [hi | lo]
#define K3_ 2304  // split W:  [hi | lo | hi]

typedef __attribute__((ext_vector_type(8))) short bf16x8;
typedef __attribute__((ext_vector_type(4))) float f32x4;
typedef unsigned short ushort_t;

__device__ __forceinline__ unsigned short f2bf(float x) {
    union { __hip_bfloat16 h; unsigned short u; } cv;
    cv.h = __float2bfloat16(x);
    return cv.u;
}
__device__ __forceinline__ float bf2f(unsigned short u) {
    union { unsigned short u; __hip_bfloat16 h; } cv;
    cv.u = u;
    return __bfloat162float(cv.h);
}

__device__ __forceinline__ void gload_lds16(const void* g, void* l) {
    __builtin_amdgcn_global_load_lds((const __attribute__((address_space(1))) void*)g,
                                     (__attribute__((address_space(3))) void*)l,
                                     16, 0, 0);
}

// ---------------------------------------------------------------------------
__global__ __launch_bounds__(256) void zero_kernel(float4* __restrict__ p) {
    p[(size_t)blockIdx.x * 256 + threadIdx.x] = make_float4(0.f, 0.f, 0.f, 0.f);
}

// out[m][n] = bf[n]  (final GEMM then atomically accumulates on top)
__global__ __launch_bounds__(256) void bias_init(
    float4* __restrict__ out4, const float4* __restrict__ bf4)
{
    const size_t idx = (size_t)blockIdx.x * 256 + threadIdx.x;  // 786432 f4
    out4[idx] = bf4[idx % 192];
}

// ---------------------------------------------------------------------------
// Split fp32 activations -> A2 = [hi | lo] bf16, row-major [M][1536].
// ---------------------------------------------------------------------------
__global__ __launch_bounds__(256) void asplit_kernel(
    const float* __restrict__ q, const float* __restrict__ k, const float* __restrict__ v,
    short* __restrict__ q2, short* __restrict__ k2, short* __restrict__ v2)
{
    const int z = blockIdx.z;
    const float* A = (z == 0) ? q : (z == 1) ? k : v;
    short* O = (z == 0) ? q2 : (z == 1) ? k2 : v2;
    const int col = blockIdx.x * 256 + threadIdx.x;
    const int m   = blockIdx.y;
    if (col >= D_) return;
    const float a = A[(size_t)m * D_ + col];
    const unsigned short hi = f2bf(a);
    const unsigned short lo = f2bf(a - bf2f(hi));
    O[(size_t)m * K2_ + col]       = (short)hi;
    O[(size_t)m * K2_ + D_ + col]  = (short)lo;
}

// ---------------------------------------------------------------------------
// Transpose + split weights -> WT3 [Npad x 2304]: row n = [hi | lo | hi].
// ---------------------------------------------------------------------------
__global__ __launch_bounds__(256) void wsplit_kernel(
    const float* __restrict__ Wq, const float* __restrict__ Wk,
    const float* __restrict__ Wv, const float* __restrict__ Wl,
    const float* __restrict__ Wf,
    short* __restrict__ WqT3, short* __restrict__ WkT3, short* __restrict__ WvT3,
    short* __restrict__ WlT3, short* __restrict__ WfT3)
{
    const int z = blockIdx.z;
    const float* W; short* O; int Nw, Npad;
    if (z == 0)      { W = Wq; O = WqT3; Nw = D_;   Npad = 768; }
    else if (z == 1) { W = Wk; O = WkT3; Nw = D_;   Npad = 768; }
    else if (z == 2) { W = Wv; O = WvT3; Nw = D_;   Npad = 768; }
    else if (z == 3) { W = Wl; O = WlT3; Nw = NSW_; Npad = 128; }
    else             { W = Wf; O = WfT3; Nw = D_;   Npad = 768; }

    const int k0 = blockIdx.x * 64;
    const int n0 = blockIdx.y * 64;
    if (n0 >= Npad) return;

    __shared__ float sm[64][65];
    const int c  = threadIdx.x & 63;
    const int r4 = threadIdx.x >> 6;

#pragma unroll
    for (int i = 0; i < 16; i++) {
        const int r = i * 4 + r4;
        float val = 0.f;
        if (n0 + c < Nw) val = W[(size_t)(k0 + r) * Nw + n0 + c];
        sm[r][c] = val;
    }
    __syncthreads();

#pragma unroll
    for (int i = 0; i < 16; i++) {
        const int nl = i * 4 + r4;
        const int n  = n0 + nl;
        if (n >= Npad) continue;
        const float v = (n < Nw) ? sm[c][nl] : 0.f;
        const unsigned short hi = f2bf(v);
        const unsigned short lo = f2bf(v - bf2f(hi));
        const size_t rb = (size_t)n * K3_;
        O[rb + k0 + c]        = (short)hi;
        O[rb + 768 + k0 + c]  = (short)lo;
        O[rb + 1536 + k0 + c] = (short)hi;
    }
}

// ---------------------------------------------------------------------------
// Split-K=2 proj GEMM (HW fp32 atomics into zeroed Cp/Cpsw; 2-term fp32
// atomic accumulation is order-commutative -> deterministic).
// ---------------------------------------------------------------------------
__global__ __launch_bounds__(256, 4) void proj_gemm(
    const short* __restrict__ q2, const short* __restrict__ k2, const short* __restrict__ v2,
    const short* __restrict__ WqT3, const short* __restrict__ WkT3,
    const short* __restrict__ WvT3, const short* __restrict__ WlT3,
    float* __restrict__ Cp, float* __restrict__ Cpsw)
{
    const int z = blockIdx.z;
    int g, part, bx = blockIdx.x;
    if (z < 6) { g = z >> 1; part = z & 1; }
    else       { if (bx >= 2) return; g = 3; part = bx; bx = 0; }

    const short* A2  = (g == 1) ? k2 : (g == 2) ? v2 : q2;
    const short* WT3 = (g == 0) ? WqT3 : (g == 1) ? WkT3 : (g == 2) ? WvT3 : WlT3;
    float* C   = (g < 3) ? (Cp + (size_t)g * 4096 * 768) : Cpsw;
    const int Ncols = (g < 3) ? 768 : NSW_;

    const int m0 = blockIdx.y * 128;
    const int n0 = bx * 128;

    __shared__ __align__(16) short As[128 * 32];
    __shared__ __align__(16) short Bs[128 * 32];

    const int tid  = threadIdx.x;
    const int lane = tid & 63;
    const int wv_  = tid >> 6;
    const int wm   = (wv_ & 1) << 6;
    const int wn   = (wv_ >> 1) << 6;
    const int l15  = lane & 15;
    const int quad = lane >> 4;

    f32x4 acc[4][4] = {};

    const int sa  = tid;
    const int sb  = tid + 256;
    const int ra  = sa >> 2, ka = (sa & 3) << 3;
    const int rb  = sb >> 2, kb8 = (sb & 3) << 3;

    const int kbeg = part * 1152;
    for (int kb = kbeg; kb < kbeg + 1152; kb += 32) {
        const int akb = (kb < 768) ? kb : kb - 768;
        __syncthreads();
        gload_lds16(A2  + (size_t)(m0 + ra) * K2_ + akb + ka,  &As[sa << 3]);
        gload_lds16(A2  + (size_t)(m0 + rb) * K2_ + akb + kb8, &As[sb << 3]);
        gload_lds16(WT3 + (size_t)(n0 + ra) * K3_ + kb  + ka,  &Bs[sa << 3]);
        gload_lds16(WT3 + (size_t)(n0 + rb) * K3_ + kb  + kb8, &Bs[sb << 3]);
        __syncthreads();

        bf16x8 af[4], bfr[4];
#pragma unroll
        for (int t = 0; t < 4; t++) {
            af[t]  = *(const bf16x8*)&As[(wm + t * 16 + l15) * 32 + quad * 8];
            bfr[t] = *(const bf16x8*)&Bs[(wn + t * 16 + l15) * 32 + quad * 8];
        }
#pragma unroll
        for (int mt = 0; mt < 4; mt++)
#pragma unroll
            for (int nt = 0; nt < 4; nt++)
                acc[mt][nt] = __builtin_amdgcn_mfma_f32_16x16x32_bf16(
                    af[mt], bfr[nt], acc[mt][nt], 0, 0, 0);
    }

#pragma unroll
    for (int nt = 0; nt < 4; nt++) {
        const int col = n0 + wn + nt * 16 + l15;
        if (col >= Ncols) continue;
#pragma unroll
        for (int mt = 0; mt < 4; mt++) {
            const int rowb = m0 + wm + mt * 16 + quad * 4;
#pragma unroll
            for (int r = 0; r < 4; r++)
                unsafeAtomicAdd(&C[(size_t)(rowb + r) * Ncols + col], acc[mt][nt][r]);
        }
    }
}

// ---------------------------------------------------------------------------
// Split-K=4 final GEMM: out += outp2 (x) WfT3 (bias pre-initialized).
// ---------------------------------------------------------------------------
__global__ __launch_bounds__(256, 4) void final_gemm(
    const short* __restrict__ A2, const short* __restrict__ WT3,
    float* __restrict__ out)
{
    const int part = blockIdx.z;
    const int m0 = blockIdx.y * 128;
    const int n0 = blockIdx.x * 128;

    __shared__ __align__(16) short As[128 * 32];
    __shared__ __align__(16) short Bs[128 * 32];

    const int tid  = threadIdx.x;
    const int lane = tid & 63;
    const int wv_  = tid >> 6;
    const int wm   = (wv_ & 1) << 6;
    const int wn   = (wv_ >> 1) << 6;
    const int l15  = lane & 15;
    const int quad = lane >> 4;

    f32x4 acc[4][4] = {};

    const int sa  = tid;
    const int sb  = tid + 256;
    const int ra  = sa >> 2, ka = (sa & 3) << 3;
    const int rb  = sb >> 2, kb8 = (sb & 3) << 3;

    const int kbeg = part * 576;
    for (int kb = kbeg; kb < kbeg + 576; kb += 32) {
        const int akb = (kb < 768) ? kb : kb - 768;
        __syncthreads();
        gload_lds16(A2  + (size_t)(m0 + ra) * K2_ + akb + ka,  &As[sa << 3]);
        gload_lds16(A2  + (size_t)(m0 + rb) * K2_ + akb + kb8, &As[sb << 3]);
        gload_lds16(WT3 + (size_t)(n0 + ra) * K3_ + kb  + ka,  &Bs[sa << 3]);
        gload_lds16(WT3 + (size_t)(n0 + rb) * K3_ + kb  + kb8, &Bs[sb << 3]);
        __syncthreads();

        bf16x8 af[4], bfr[4];
#pragma unroll
        for (int t = 0; t < 4; t++) {
            af[t]  = *(const bf16x8*)&As[(wm + t * 16 + l15) * 32 + quad * 8];
            bfr[t] = *(const bf16x8*)&Bs[(wn + t * 16 + l15) * 32 + quad * 8];
        }
#pragma unroll
        for (int mt = 0; mt < 4; mt++)
#pragma unroll
            for (int nt = 0; nt < 4; nt++)
                acc[mt][nt] = __builtin_amdgcn_mfma_f32_16x16x32_bf16(
                    af[mt], bfr[nt], acc[mt][nt], 0, 0, 0);
    }

#pragma unroll
    for (int nt = 0; nt < 4; nt++) {
        const int col = n0 + wn + nt * 16 + l15;
#pragma unroll
        for (int mt = 0; mt < 4; mt++) {
            const int rowb = m0 + wm + mt * 16 + quad * 4;
#pragma unroll
            for (int r = 0; r < 4; r++)
                unsafeAtomicAdd(&out[(size_t)(rowb + r) * D_ + col], acc[mt][nt][r]);
        }
    }
}

// ---------------------------------------------------------------------------
// convert_qk: qs2a/ks2a [h][b][l][hi64|lo64] = split(Cp[g] + bias_g)
// ---------------------------------------------------------------------------
__global__ __launch_bounds__(256) void convert_qk(
    const float* __restrict__ Cp, const float* __restrict__ bq,
    const float* __restrict__ bk,
    ushort_t* __restrict__ qs2a, ushort_t* __restrict__ ks2a)
{
    const int g = blockIdx.z;
    const float* src  = Cp + (size_t)g * 4096 * 768;
    const float* bias = g ? bk : bq;
    ushort_t* dst = g ? ks2a : qs2a;
    const int r0 = blockIdx.x * 8;

#pragma unroll
    for (int j = 0; j < 6; j++) {
        const int idx = threadIdx.x + 256 * j;       // 0..1535
        const int row = r0 + idx / 192;
        const int c4  = (idx % 192) * 4;
        float4 x = *(const float4*)&src[(size_t)row * 768 + c4];
        const float4 b4 = *(const float4*)&bias[c4];
        x.x += b4.x; x.y += b4.y; x.z += b4.z; x.w += b4.w;
        const int hh = c4 >> 6, dd = c4 & 63;
        const int bb = row >> 9, ll = row & 511;
        const size_t base = (((size_t)hh * B_ + bb) * 512 + ll) * 128 + dd;
        ushort_t hi[4], lo[4];
        const float xv[4] = {x.x, x.y, x.z, x.w};
#pragma unroll
        for (int u = 0; u < 4; u++) {
            hi[u] = f2bf(xv[u]);
            lo[u] = f2bf(xv[u] - bf2f(hi[u]));
        }
        *(ushort4*)&dst[base]      = *(ushort4*)hi;
        *(ushort4*)&dst[base + 64] = *(ushort4*)lo;
    }
}

// ---------------------------------------------------------------------------
// convert_v: vt2 [h][b][c(hi) / 64+c(lo)][t] = transpose(split(Cp[2] + bv))
// ---------------------------------------------------------------------------
__global__ __launch_bounds__(256) void convert_v(
    const float* __restrict__ Cp, const float* __restrict__ bv,
    ushort_t* __restrict__ vt2)
{
    const int t0 = blockIdx.x * 64;
    const int b  = blockIdx.y;
    const int h  = blockIdx.z;
    const float* src = Cp + (size_t)2 * 4096 * 768;

    __shared__ float sm[64][65];
    const int tid = threadIdx.x;
    {
        const int r = tid >> 2, cseg = (tid & 3) * 16;
        const size_t rowb = (size_t)(b * 512 + t0 + r) * 768 + h * 64 + cseg;
#pragma unroll
        for (int u = 0; u < 4; u++) {
            float4 x = *(const float4*)&src[rowb + u * 4];
            sm[r][cseg + u * 4 + 0] = x.x;
            sm[r][cseg + u * 4 + 1] = x.y;
            sm[r][cseg + u * 4 + 2] = x.z;
            sm[r][cseg + u * 4 + 3] = x.w;
        }
    }
    __syncthreads();
    {
        const int c = tid >> 2, seg = (tid & 3) * 16;
        const float bvv = bv[h * 64 + c];
        ushort_t hib[16], lob[16];
#pragma unroll
        for (int i = 0; i < 16; i++) {
            const float val = sm[seg + i][c] + bvv;
            hib[i] = f2bf(val);
            lob[i] = f2bf(val - bf2f(hib[i]));
        }
        const size_t bh = (((size_t)h * B_ + b) * 128 + c) * 512 + t0 + seg;
        const size_t bl = bh + (size_t)64 * 512;
#pragma unroll
        for (int u = 0; u < 4; u++) {
            *(ushort4*)&vt2[bh + u * 4] = *(ushort4*)&hib[u * 4];
            *(ushort4*)&vt2[bl + u * 4] = *(ushort4*)&lob[u * 4];
        }
    }
}

__global__ __launch_bounds__(256) void convert_sw(
    const float* __restrict__ Cpsw, const float* __restrict__ bl,
    float* __restrict__ swv)
{
    const int idx = blockIdx.x * 256 + threadIdx.x;   // < 294912
    swv[idx] = Cpsw[idx] + bl[idx % NSW_];
}

// ---------------------------------------------------------------------------
// sig16[h][b][l][t] = mask ? 0 : max(sigmoid(bias_h + w_h · ploc[b,l,t,:]), 1e-6)
// ---------------------------------------------------------------------------
__global__ __launch_bounds__(256) void sig_kernel(
    const float* __restrict__ ploc, const float* __restrict__ swv,
    const int* __restrict__ maskp, _Float16* __restrict__ sig16)
{
    const int b = blockIdx.y;
    const int l = blockIdx.x;
    const int tid = threadIdx.x;

    __shared__ float pls[512 * 5];
    __shared__ float sws[72];
    __shared__ int   msk[512];

    const float* src = ploc + (size_t)(b * 512 + l) * 512 * 5;
    for (int i = tid; i < 640; i += 256)
        *(float4*)&pls[i * 4] = *(const float4*)(src + i * 4);
    if (tid < 72) sws[tid] = swv[(size_t)(b * 512 + l) * NSW_ + tid];
    for (int i = tid; i < 512; i += 256) msk[i] = maskp[b * 512 + i];
    __syncthreads();

    for (int e = tid; e < H_ * 512; e += 256) {
        const int t  = e & 511;
        const int hh = e >> 9;
        float s = sws[hh * 6];
#pragma unroll
        for (int d = 0; d < SD_; d++) s += sws[hh * 6 + 1 + d] * pls[t * 5 + d];
        const float sig = msk[t] ? 0.f : fmaxf(1.f / (1.f + __expf(-s)), 1e-6f);
        sig16[(((size_t)hh * B_ + b) * 512 + l) * 512 + t] = (_Float16)sig;
    }
}

// ---------------------------------------------------------------------------
// MFMA attention. 1-D grid id = ltile*96 + hb so all 8 l-tiles of one (h,b)
// land on the same XCD (round-robin id%8) -> K/V slab shared in L2.
// Unnormalized p kept in 128 VGPRs across the full t-loop; row sums via
// shuffle+LDS; fused written normalized EXACTLY ONCE (no reread).
// ---------------------------------------------------------------------------
__global__ __launch_bounds__(256, 2) void attn_kernel(
    const ushort_t* __restrict__ qs2, const ushort_t* __restrict__ ks2,
    const ushort_t* __restrict__ vt2, const _Float16* __restrict__ sig16,
    float* __restrict__ fused, ushort_t* __restrict__ outp2)
{
    const int id = blockIdx.x;      // 0..767
    const int hb = id % 96;
    const int lt = id / 96;
    const int h  = hb >> 3;
    const int b  = hb & 7;
    const int l0 = lt << 6;
    const int tid  = threadIdx.x;
    const int lane = tid & 63;
    const int wv   = tid >> 6;
    const int l15  = lane & 15;
    const int quad = lane >> 4;

    __shared__ __align__(16) ushort_t qs[64 * 128];
    __shared__ __align__(16) ushort_t ks[64 * 128];
    __shared__ __align__(16) ushort_t vts[128 * 64];
    __shared__ __align__(16) ushort_t ps[64 * 136];   // [l][hi64 | lo64 | pad]
    __shared__ __align__(16) _Float16 ss[64 * 64];    // sig tile [l][t]
    __shared__ float ssb[4 * 64];
    __shared__ float ssum[64];

    // stage Q tile once (swizzled chunks)
    {
        const size_t qbase = ((size_t)hb * 512 + l0) * 128;
#pragma unroll
        for (int j = 0; j < 4; j++) {
            const int i = tid + 256 * j;
            const int r = i >> 4, c = i & 15, gc = c ^ (r & 7);
            gload_lds16(qs2 + qbase + r * 128 + gc * 8, &qs[i * 8]);
        }
    }

    f32x4 preg[8][4];   // unnormalized p, C-layout: [t-tile][mt][r2]
    f32x4 accpv[4] = {};

#pragma unroll
    for (int tt = 0; tt < 8; tt++) {
        const int t0 = tt << 6;
        __syncthreads();
        {
            const size_t kbase = ((size_t)hb * 512 + t0) * 128;
#pragma unroll
            for (int j = 0; j < 4; j++) {
                const int i = tid + 256 * j;
                const int r = i >> 4, c = i & 15, gc = c ^ (r & 7);
                gload_lds16(ks2 + kbase + r * 128 + gc * 8, &ks[i * 8]);
            }
            const size_t vbase = (size_t)hb * 128 * 512;
#pragma unroll
            for (int j = 0; j < 4; j++) {
                const int i = tid + 256 * j;
                const int r = i >> 3, c = i & 7, gc = c ^ (r & 7);
                gload_lds16(vt2 + vbase + (size_t)r * 512 + t0 + gc * 8, &vts[i * 8]);
            }
            // sig tile: 64 rows x 64 f16 = 8 KB = 512 x 16B chunks
            const _Float16* sgb = sig16 + ((size_t)hb * 512 + l0) * 512 + t0;
#pragma unroll
            for (int j = 0; j < 2; j++) {
                const int i = tid + 256 * j;
                const int r = i >> 3, c = i & 7;
                gload_lds16(sgb + (size_t)r * 512 + c * 8, &ss[i * 8]);
            }
        }
        __syncthreads();

        // ---- QK ----
        f32x4 acq[4] = {};
        {
            const int trow = wv * 16 + l15;
            const int tsw  = trow & 7;
            const bf16x8 bk0 = *(const bf16x8*)&ks[trow * 128 + ((0  + quad) ^ tsw) * 8];
            const bf16x8 bk1 = *(const bf16x8*)&ks[trow * 128 + ((4  + quad) ^ tsw) * 8];
            const bf16x8 bk2 = *(const bf16x8*)&ks[trow * 128 + ((8  + quad) ^ tsw) * 8];
            const bf16x8 bk3 = *(const bf16x8*)&ks[trow * 128 + ((12 + quad) ^ tsw) * 8];
#pragma unroll
            for (int mt = 0; mt < 4; mt++) {
                const int arow = mt * 16 + l15;
                const int asw  = arow & 7;
                const bf16x8 a0 = *(const bf16x8*)&qs[arow * 128 + ((0  + quad) ^ asw) * 8];
                const bf16x8 a1 = *(const bf16x8*)&qs[arow * 128 + ((4  + quad) ^ asw) * 8];
                const bf16x8 a2 = *(const bf16x8*)&qs[arow * 128 + ((8  + quad) ^ asw) * 8];
                const bf16x8 a3 = *(const bf16x8*)&qs[arow * 128 + ((12 + quad) ^ asw) * 8];
                f32x4 a = acq[mt];
                a = __builtin_amdgcn_mfma_f32_16x16x32_bf16(a0, bk0, a, 0, 0, 0);
                a = __builtin_amdgcn_mfma_f32_16x16x32_bf16(a1, bk1, a, 0, 0, 0);
                a = __builtin_amdgcn_mfma_f32_16x16x32_bf16(a0, bk2, a, 0, 0, 0);
                a = __builtin_amdgcn_mfma_f32_16x16x32_bf16(a1, bk3, a, 0, 0, 0);
                a = __builtin_amdgcn_mfma_f32_16x16x32_bf16(a2, bk0, a, 0, 0, 0);
                a = __builtin_amdgcn_mfma_f32_16x16x32_bf16(a3, bk1, a, 0, 0, 0);
                acq[mt] = a;
            }
        }

        // ---- p = sig * exp(qk/8): keep fp32 in regs, split hi/lo to LDS ----
        {
            const int tcol = wv * 16 + l15;
#pragma unroll
            for (int mt = 0; mt < 4; mt++)
#pragma unroll
                for (int r2 = 0; r2 < 4; r2++) {
                    const int lrow = mt * 16 + quad * 4 + r2;
                    const float sg = (float)ss[lrow * 64 + tcol];
                    const float p  = sg * __expf(acq[mt][r2] * 0.125f);
                    preg[tt][mt][r2] = p;
                    const ushort_t hi = f2bf(p);
                    const ushort_t lo = f2bf(p - bf2f(hi));
                    ps[lrow * 136 + tcol]      = hi;
                    ps[lrow * 136 + 64 + tcol] = lo;
                }
        }
        __syncthreads();

        // ---- PV ----
        {
            const int vrh = wv * 16 + l15;
            const int vrl = 64 + vrh;
            const int swh = vrh & 7, swl = vrl & 7;
            const bf16x8 bh0 = *(const bf16x8*)&vts[vrh * 64 + ((0 + quad) ^ swh) * 8];
            const bf16x8 bh1 = *(const bf16x8*)&vts[vrh * 64 + ((4 + quad) ^ swh) * 8];
            const bf16x8 bl0 = *(const bf16x8*)&vts[vrl * 64 + ((0 + quad) ^ swl) * 8];
            const bf16x8 bl1 = *(const bf16x8*)&vts[vrl * 64 + ((4 + quad) ^ swl) * 8];
#pragma unroll
            for (int mt = 0; mt < 4; mt++) {
                const int prow = mt * 16 + l15;
                const bf16x8 ph0 = *(const bf16x8*)&ps[prow * 136 + 0  + quad * 8];
                const bf16x8 ph1 = *(const bf16x8*)&ps[prow * 136 + 32 + quad * 8];
                const bf16x8 pl0 = *(const bf16x8*)&ps[prow * 136 + 64 + quad * 8];
                const bf16x8 pl1 = *(const bf16x8*)&ps[prow * 136 + 96 + quad * 8];
                f32x4 a = accpv[mt];
                a = __builtin_amdgcn_mfma_f32_16x16x32_bf16(ph0, bh0, a, 0, 0, 0);
                a = __builtin_amdgcn_mfma_f32_16x16x32_bf16(ph1, bh1, a, 0, 0, 0);
                a = __builtin_amdgcn_mfma_f32_16x16x32_bf16(ph0, bl0, a, 0, 0, 0);
                a = __builtin_amdgcn_mfma_f32_16x16x32_bf16(ph1, bl1, a, 0, 0, 0);
                a = __builtin_amdgcn_mfma_f32_16x16x32_bf16(pl0, bh0, a, 0, 0, 0);
                a = __builtin_amdgcn_mfma_f32_16x16x32_bf16(pl1, bh1, a, 0, 0, 0);
                accpv[mt] = a;
            }
        }
    }

    // ---- row sums: per-thread partial over 8 tiles, shuffle over 16 t-lanes,
    //      LDS combine over 4 waves ----
    float part[4][4];
#pragma unroll
    for (int mt = 0; mt < 4; mt++)
#pragma unroll
        for (int r2 = 0; r2 < 4; r2++) {
            float s = 0.f;
#pragma unroll
            for (int tt = 0; tt < 8; tt++) s += preg[tt][mt][r2];
#pragma unroll
            for (int off = 1; off < 16; off <<= 1)
                s += __shfl_xor(s, off, 64);
            part[mt][r2] = s;     // all lanes in a quad now hold the wave-sum
        }
    __syncthreads();
    if (l15 == 0) {
#pragma unroll
        for (int mt = 0; mt < 4; mt++)
#pragma unroll
            for (int r2 = 0; r2 < 4; r2++)
                ssb[wv * 64 + mt * 16 + quad * 4 + r2] = part[mt][r2];
    }
    __syncthreads();
    if (tid < 64)
        ssum[tid] = ssb[tid] + ssb[64 + tid] + ssb[128 + tid] + ssb[192 + tid];
    __syncthreads();

    float inv[4][4];
#pragma unroll
    for (int mt = 0; mt < 4; mt++)
#pragma unroll
        for (int r2 = 0; r2 < 4; r2++)
            inv[mt][r2] = 1.f / ssum[mt * 16 + quad * 4 + r2];

    // ---- normalized fused store (single pass) ----
    {
        float* fb = fused + ((size_t)hb * 512 + l0) * 512 + wv * 16 + l15;
#pragma unroll
        for (int tt = 0; tt < 8; tt++)
#pragma unroll
            for (int mt = 0; mt < 4; mt++)
#pragma unroll
                for (int r2 = 0; r2 < 4; r2++)
                    fb[(size_t)(mt * 16 + quad * 4 + r2) * 512 + tt * 64] =
                        preg[tt][mt][r2] * inv[mt][r2];
    }

    // ---- normalized PV output, split hi/lo for final GEMM ----
#pragma unroll
    for (int mt = 0; mt < 4; mt++)
#pragma unroll
        for (int r2 = 0; r2 < 4; r2++) {
            const int lrow = mt * 16 + quad * 4 + r2;
            const float val = accpv[mt][r2] * inv[mt][r2];
            const ushort_t hi = f2bf(val);
            const ushort_t lo = f2bf(val - bf2f(hi));
            const size_t obase = ((size_t)(b * 512 + l0 + lrow)) * K2_ + h * 64 + wv * 16 + l15;
            outp2[obase]       = hi;
            outp2[obase + D_]  = lo;
        }
}

// ---------------------------------------------------------------------------
extern "C" void kernel_launch(void* const* d_in, const int* in_sizes, int n_in,
                              void* d_out, int out_size, void* d_ws, size_t ws_size,
                              hipStream_t stream) {
    const float* q    = (const float*)d_in[0];
    const float* k    = (const float*)d_in[1];
    const float* v    = (const float*)d_in[2];
    const float* ploc = (const float*)d_in[3];
    const int*   mask = (const int*)  d_in[4];
    const float* Wq   = (const float*)d_in[5];
    const float* bq   = (const float*)d_in[6];
    const float* Wk   = (const float*)d_in[7];
    const float* bk   = (const float*)d_in[8];
    const float* Wv   = (const float*)d_in[9];
    const float* bv   = (const float*)d_in[10];
    const float* Wl   = (const float*)d_in[11];
    const float* bl   = (const float*)d_in[12];
    const float* Wf   = (const float*)d_in[13];
    const float* bf   = (const float*)d_in[14];

    char* base = (char*)d_ws;
    short*    q2    = (short*)(base + 0);             // 12,582,912
    short*    k2    = (short*)(base + 12582912);
    short*    v2    = (short*)(base + 25165824);
    short*    WqT3  = (short*)(base + 37748736);      //  3,538,944
    short*    WkT3  = (short*)(base + 41287680);
    short*    WvT3  = (short*)(base + 44826624);
    short*    WlT3  = (short*)(base + 48365568);      //    589,824
    short*    WfT3  = (short*)(base + 48955392);      //  3,538,944 (live -> final)
    float*    Cp    = (float*)(base + 52494336);      // 37,748,736 (3x 4096x768 f32)
    float*    Cpsw  = (float*)(base + 90243072);      //  1,179,648
    ushort_t* qs2a  = (ushort_t*)q2;                  // overlay (q2 dead after proj)
    ushort_t* ks2a  = (ushort_t*)k2;
    ushort_t* vt2   = (ushort_t*)v2;
    float*    swv   = (float*)WqT3;                   // overlay
    _Float16* sig16 = (_Float16*)(base + 52494336);   // 50,331,648 overlay over Cp+
    ushort_t* outp2 = (ushort_t*)(base + 102825984);  // 12,582,912 -> total 115,408,896

    float* out   = (float*)d_out;
    float* fused = out + (size_t)4096 * D_;

    zero_kernel<<<dim3(9504), 256, 0, stream>>>((float4*)Cp);   // Cp + Cpsw
    bias_init<<<dim3(3072), 256, 0, stream>>>((float4*)out, (const float4*)bf);

    asplit_kernel<<<dim3(3, 4096, 3), 256, 0, stream>>>(q, k, v, q2, k2, v2);
    wsplit_kernel<<<dim3(12, 12, 5), 256, 0, stream>>>(
        Wq, Wk, Wv, Wl, Wf, WqT3, WkT3, WvT3, WlT3, WfT3);

    proj_gemm<<<dim3(6, 32, 7), 256, 0, stream>>>(
        q2, k2, v2, WqT3, WkT3, WvT3, WlT3, Cp, Cpsw);

    convert_qk<<<dim3(512, 1, 2), 256, 0, stream>>>(Cp, bq, bk, qs2a, ks2a);
    convert_v<<<dim3(8, 8, 12), 256, 0, stream>>>(Cp, bv, vt2);
    convert_sw<<<dim3(1152), 256, 0, stream>>>(Cpsw, bl, swv);

    sig_kernel<<<dim3(512, 8), 256, 0, stream>>>(ploc, swv, mask, sig16);

    attn_kernel<<<dim3(768), 256, 0, stream>>>(
        qs2a, ks2a, vt2, sig16, fused, outp2);

    final_gemm<<<dim3(6, 32, 4), 256, 0, stream>>>((const short*)outp2, WfT3, out);
}

// Round 6
// 523.074 us; speedup vs baseline: 1.0764x; 1.0258x over previous
//
#include <hip/hip_runtime.h>
#include <hip/hip_bf16.h>

#define B_ 8
#define L_ 512
#define T_ 512
#define D_ 768
#define H_ 12
#define DH_ 64
#define SD_ 5
#define NSW_ 72   // H*(SD+1)
#define K2_ 1536  // split A:  [hi | lo]
#define K3_ 2304  // split W:  [hi | lo | hi]

typedef __attribute__((ext_vector_type(8))) short bf16x8;
typedef __attribute__((ext_vector_type(4))) float f32x4;
typedef unsigned short ushort_t;

__device__ __forceinline__ unsigned short f2bf(float x) {
    union { __hip_bfloat16 h; unsigned short u; } cv;
    cv.h = __float2bfloat16(x);
    return cv.u;
}
__device__ __forceinline__ float bf2f(unsigned short u) {
    union { unsigned short u; __hip_bfloat16 h; } cv;
    cv.u = u;
    return __bfloat162float(cv.h);
}

__device__ __forceinline__ void gload_lds16(const void* g, void* l) {
    __builtin_amdgcn_global_load_lds((const __attribute__((address_space(1))) void*)g,
                                     (__attribute__((address_space(3))) void*)l,
                                     16, 0, 0);
}

// ---------------------------------------------------------------------------
__global__ __launch_bounds__(256) void zero_kernel(float4* __restrict__ p) {
    p[(size_t)blockIdx.x * 256 + threadIdx.x] = make_float4(0.f, 0.f, 0.f, 0.f);
}

// out[m][n] = bf[n]  (final GEMM then atomically accumulates on top)
__global__ __launch_bounds__(256) void bias_init(
    float4* __restrict__ out4, const float4* __restrict__ bf4)
{
    const size_t idx = (size_t)blockIdx.x * 256 + threadIdx.x;  // 786432 f4
    out4[idx] = bf4[idx % 192];
}

// ---------------------------------------------------------------------------
// Split fp32 activations -> A2 = [hi | lo] bf16, row-major [M][1536].
// ---------------------------------------------------------------------------
__global__ __launch_bounds__(256) void asplit_kernel(
    const float* __restrict__ q, const float* __restrict__ k, const float* __restrict__ v,
    short* __restrict__ q2, short* __restrict__ k2, short* __restrict__ v2)
{
    const int z = blockIdx.z;
    const float* A = (z == 0) ? q : (z == 1) ? k : v;
    short* O = (z == 0) ? q2 : (z == 1) ? k2 : v2;
    const int col = blockIdx.x * 256 + threadIdx.x;
    const int m   = blockIdx.y;
    if (col >= D_) return;
    const float a = A[(size_t)m * D_ + col];
    const unsigned short hi = f2bf(a);
    const unsigned short lo = f2bf(a - bf2f(hi));
    O[(size_t)m * K2_ + col]       = (short)hi;
    O[(size_t)m * K2_ + D_ + col]  = (short)lo;
}

// ---------------------------------------------------------------------------
// Transpose + split weights -> WT3 [Npad x 2304]: row n = [hi | lo | hi].
// ---------------------------------------------------------------------------
__global__ __launch_bounds__(256) void wsplit_kernel(
    const float* __restrict__ Wq, const float* __restrict__ Wk,
    const float* __restrict__ Wv, const float* __restrict__ Wl,
    const float* __restrict__ Wf,
    short* __restrict__ WqT3, short* __restrict__ WkT3, short* __restrict__ WvT3,
    short* __restrict__ WlT3, short* __restrict__ WfT3)
{
    const int z = blockIdx.z;
    const float* W; short* O; int Nw, Npad;
    if (z == 0)      { W = Wq; O = WqT3; Nw = D_;   Npad = 768; }
    else if (z == 1) { W = Wk; O = WkT3; Nw = D_;   Npad = 768; }
    else if (z == 2) { W = Wv; O = WvT3; Nw = D_;   Npad = 768; }
    else if (z == 3) { W = Wl; O = WlT3; Nw = NSW_; Npad = 128; }
    else             { W = Wf; O = WfT3; Nw = D_;   Npad = 768; }

    const int k0 = blockIdx.x * 64;
    const int n0 = blockIdx.y * 64;
    if (n0 >= Npad) return;

    __shared__ float sm[64][65];
    const int c  = threadIdx.x & 63;
    const int r4 = threadIdx.x >> 6;

#pragma unroll
    for (int i = 0; i < 16; i++) {
        const int r = i * 4 + r4;
        float val = 0.f;
        if (n0 + c < Nw) val = W[(size_t)(k0 + r) * Nw + n0 + c];
        sm[r][c] = val;
    }
    __syncthreads();

#pragma unroll
    for (int i = 0; i < 16; i++) {
        const int nl = i * 4 + r4;
        const int n  = n0 + nl;
        if (n >= Npad) continue;
        const float v = (n < Nw) ? sm[c][nl] : 0.f;
        const unsigned short hi = f2bf(v);
        const unsigned short lo = f2bf(v - bf2f(hi));
        const size_t rb = (size_t)n * K3_;
        O[rb + k0 + c]        = (short)hi;
        O[rb + 768 + k0 + c]  = (short)lo;
        O[rb + 1536 + k0 + c] = (short)hi;
    }
}

// ---------------------------------------------------------------------------
// Split-K=2 proj GEMM, XCD-swizzled 1-D grid (1216 blocks).
// id < 1152: id = 48c + 8j + r -> group = 8c + r in [0,192), bx = j.
//   group: zslot = group>>5 (0..5), by = group&31; g = zslot>>1, part = zslot&1.
//   The 6 bx blocks of a group share residue r -> SAME XCD -> A-tile fetched
//   from HBM once per group instead of 6x.
// id >= 1152: Wl tail, t = id-1152: part = t&1, by = t>>1, bx = 0.
// Accumulates fp32 via HW atomics into zeroed Cp/Cpsw (2-term fp32 atomic
// accumulation is order-commutative -> deterministic).
// ---------------------------------------------------------------------------
__global__ __launch_bounds__(256, 4) void proj_gemm(
    const short* __restrict__ q2, const short* __restrict__ k2, const short* __restrict__ v2,
    const short* __restrict__ WqT3, const short* __restrict__ WkT3,
    const short* __restrict__ WvT3, const short* __restrict__ WlT3,
    float* __restrict__ Cp, float* __restrict__ Cpsw)
{
    const int id = blockIdx.x;
    int g, part, by, bx;
    if (id < 1152) {
        const int c = id / 48, w = id % 48, r = w & 7, j = w >> 3;
        const int group = c * 8 + r;      // 0..191
        const int zslot = group >> 5;     // 0..5
        by = group & 31;
        g = zslot >> 1; part = zslot & 1; bx = j;
    } else {
        const int t = id - 1152;          // 0..63
        g = 3; part = t & 1; by = t >> 1; bx = 0;
    }

    const short* A2  = (g == 1) ? k2 : (g == 2) ? v2 : q2;
    const short* WT3 = (g == 0) ? WqT3 : (g == 1) ? WkT3 : (g == 2) ? WvT3 : WlT3;
    float* C   = (g < 3) ? (Cp + (size_t)g * 4096 * 768) : Cpsw;
    const int Ncols = (g < 3) ? 768 : NSW_;

    const int m0 = by * 128;
    const int n0 = bx * 128;

    __shared__ __align__(16) short As[128 * 32];
    __shared__ __align__(16) short Bs[128 * 32];

    const int tid  = threadIdx.x;
    const int lane = tid & 63;
    const int wv_  = tid >> 6;
    const int wm   = (wv_ & 1) << 6;
    const int wn   = (wv_ >> 1) << 6;
    const int l15  = lane & 15;
    const int quad = lane >> 4;

    f32x4 acc[4][4] = {};

    const int sa  = tid;
    const int sb  = tid + 256;
    const int ra  = sa >> 2, ka = (sa & 3) << 3;
    const int rb  = sb >> 2, kb8 = (sb & 3) << 3;

    const int kbeg = part * 1152;
    for (int kb = kbeg; kb < kbeg + 1152; kb += 32) {
        const int akb = (kb < 768) ? kb : kb - 768;
        __syncthreads();
        gload_lds16(A2  + (size_t)(m0 + ra) * K2_ + akb + ka,  &As[sa << 3]);
        gload_lds16(A2  + (size_t)(m0 + rb) * K2_ + akb + kb8, &As[sb << 3]);
        gload_lds16(WT3 + (size_t)(n0 + ra) * K3_ + kb  + ka,  &Bs[sa << 3]);
        gload_lds16(WT3 + (size_t)(n0 + rb) * K3_ + kb  + kb8, &Bs[sb << 3]);
        __syncthreads();

        bf16x8 af[4], bfr[4];
#pragma unroll
        for (int t = 0; t < 4; t++) {
            af[t]  = *(const bf16x8*)&As[(wm + t * 16 + l15) * 32 + quad * 8];
            bfr[t] = *(const bf16x8*)&Bs[(wn + t * 16 + l15) * 32 + quad * 8];
        }
#pragma unroll
        for (int mt = 0; mt < 4; mt++)
#pragma unroll
            for (int nt = 0; nt < 4; nt++)
                acc[mt][nt] = __builtin_amdgcn_mfma_f32_16x16x32_bf16(
                    af[mt], bfr[nt], acc[mt][nt], 0, 0, 0);
    }

#pragma unroll
    for (int nt = 0; nt < 4; nt++) {
        const int col = n0 + wn + nt * 16 + l15;
        if (col >= Ncols) continue;
#pragma unroll
        for (int mt = 0; mt < 4; mt++) {
            const int rowb = m0 + wm + mt * 16 + quad * 4;
#pragma unroll
            for (int r = 0; r < 4; r++)
                unsafeAtomicAdd(&C[(size_t)(rowb + r) * Ncols + col], acc[mt][nt][r]);
        }
    }
}

// ---------------------------------------------------------------------------
// Split-K=4 final GEMM, XCD-swizzled 1-D grid (768 blocks):
// id = 48c + 8j + r -> group = 8c + r in [0,128): part = group>>5, by = group&31,
// bx = j. Same-A blocks share an XCD. out += outp2 (x) WfT3 (bias pre-init).
// ---------------------------------------------------------------------------
__global__ __launch_bounds__(256, 4) void final_gemm(
    const short* __restrict__ A2, const short* __restrict__ WT3,
    float* __restrict__ out)
{
    const int id = blockIdx.x;        // 0..767
    const int c = id / 48, w = id % 48, r8 = w & 7, j = w >> 3;
    const int group = c * 8 + r8;     // 0..127
    const int part = group >> 5;
    const int by   = group & 31;
    const int bx   = j;

    const int m0 = by * 128;
    const int n0 = bx * 128;

    __shared__ __align__(16) short As[128 * 32];
    __shared__ __align__(16) short Bs[128 * 32];

    const int tid  = threadIdx.x;
    const int lane = tid & 63;
    const int wv_  = tid >> 6;
    const int wm   = (wv_ & 1) << 6;
    const int wn   = (wv_ >> 1) << 6;
    const int l15  = lane & 15;
    const int quad = lane >> 4;

    f32x4 acc[4][4] = {};

    const int sa  = tid;
    const int sb  = tid + 256;
    const int ra  = sa >> 2, ka = (sa & 3) << 3;
    const int rb  = sb >> 2, kb8 = (sb & 3) << 3;

    const int kbeg = part * 576;
    for (int kb = kbeg; kb < kbeg + 576; kb += 32) {
        const int akb = (kb < 768) ? kb : kb - 768;
        __syncthreads();
        gload_lds16(A2  + (size_t)(m0 + ra) * K2_ + akb + ka,  &As[sa << 3]);
        gload_lds16(A2  + (size_t)(m0 + rb) * K2_ + akb + kb8, &As[sb << 3]);
        gload_lds16(WT3 + (size_t)(n0 + ra) * K3_ + kb  + ka,  &Bs[sa << 3]);
        gload_lds16(WT3 + (size_t)(n0 + rb) * K3_ + kb  + kb8, &Bs[sb << 3]);
        __syncthreads();

        bf16x8 af[4], bfr[4];
#pragma unroll
        for (int t = 0; t < 4; t++) {
            af[t]  = *(const bf16x8*)&As[(wm + t * 16 + l15) * 32 + quad * 8];
            bfr[t] = *(const bf16x8*)&Bs[(wn + t * 16 + l15) * 32 + quad * 8];
        }
#pragma unroll
        for (int mt = 0; mt < 4; mt++)
#pragma unroll
            for (int nt = 0; nt < 4; nt++)
                acc[mt][nt] = __builtin_amdgcn_mfma_f32_16x16x32_bf16(
                    af[mt], bfr[nt], acc[mt][nt], 0, 0, 0);
    }

#pragma unroll
    for (int nt = 0; nt < 4; nt++) {
        const int col = n0 + wn + nt * 16 + l15;
#pragma unroll
        for (int mt = 0; mt < 4; mt++) {
            const int rowb = m0 + wm + mt * 16 + quad * 4;
#pragma unroll
            for (int r = 0; r < 4; r++)
                unsafeAtomicAdd(&out[(size_t)(rowb + r) * D_ + col], acc[mt][nt][r]);
        }
    }
}

// ---------------------------------------------------------------------------
// convert_qk: qs2a/ks2a [h][b][l][hi64|lo64] = split(Cp[g] + bias_g)
// ---------------------------------------------------------------------------
__global__ __launch_bounds__(256) void convert_qk(
    const float* __restrict__ Cp, const float* __restrict__ bq,
    const float* __restrict__ bk,
    ushort_t* __restrict__ qs2a, ushort_t* __restrict__ ks2a)
{
    const int g = blockIdx.z;
    const float* src  = Cp + (size_t)g * 4096 * 768;
    const float* bias = g ? bk : bq;
    ushort_t* dst = g ? ks2a : qs2a;
    const int r0 = blockIdx.x * 8;

#pragma unroll
    for (int j = 0; j < 6; j++) {
        const int idx = threadIdx.x + 256 * j;       // 0..1535
        const int row = r0 + idx / 192;
        const int c4  = (idx % 192) * 4;
        float4 x = *(const float4*)&src[(size_t)row * 768 + c4];
        const float4 b4 = *(const float4*)&bias[c4];
        x.x += b4.x; x.y += b4.y; x.z += b4.z; x.w += b4.w;
        const int hh = c4 >> 6, dd = c4 & 63;
        const int bb = row >> 9, ll = row & 511;
        const size_t base = (((size_t)hh * B_ + bb) * 512 + ll) * 128 + dd;
        ushort_t hi[4], lo[4];
        const float xv[4] = {x.x, x.y, x.z, x.w};
#pragma unroll
        for (int u = 0; u < 4; u++) {
            hi[u] = f2bf(xv[u]);
            lo[u] = f2bf(xv[u] - bf2f(hi[u]));
        }
        *(ushort4*)&dst[base]      = *(ushort4*)hi;
        *(ushort4*)&dst[base + 64] = *(ushort4*)lo;
    }
}

// ---------------------------------------------------------------------------
// convert_v: vt2 [h][b][c(hi) / 64+c(lo)][t] = transpose(split(Cp[2] + bv))
// ---------------------------------------------------------------------------
__global__ __launch_bounds__(256) void convert_v(
    const float* __restrict__ Cp, const float* __restrict__ bv,
    ushort_t* __restrict__ vt2)
{
    const int t0 = blockIdx.x * 64;
    const int b  = blockIdx.y;
    const int h  = blockIdx.z;
    const float* src = Cp + (size_t)2 * 4096 * 768;

    __shared__ float sm[64][65];
    const int tid = threadIdx.x;
    {
        const int r = tid >> 2, cseg = (tid & 3) * 16;
        const size_t rowb = (size_t)(b * 512 + t0 + r) * 768 + h * 64 + cseg;
#pragma unroll
        for (int u = 0; u < 4; u++) {
            float4 x = *(const float4*)&src[rowb + u * 4];
            sm[r][cseg + u * 4 + 0] = x.x;
            sm[r][cseg + u * 4 + 1] = x.y;
            sm[r][cseg + u * 4 + 2] = x.z;
            sm[r][cseg + u * 4 + 3] = x.w;
        }
    }
    __syncthreads();
    {
        const int c = tid >> 2, seg = (tid & 3) * 16;
        const float bvv = bv[h * 64 + c];
        ushort_t hib[16], lob[16];
#pragma unroll
        for (int i = 0; i < 16; i++) {
            const float val = sm[seg + i][c] + bvv;
            hib[i] = f2bf(val);
            lob[i] = f2bf(val - bf2f(hib[i]));
        }
        const size_t bh = (((size_t)h * B_ + b) * 128 + c) * 512 + t0 + seg;
        const size_t bl = bh + (size_t)64 * 512;
#pragma unroll
        for (int u = 0; u < 4; u++) {
            *(ushort4*)&vt2[bh + u * 4] = *(ushort4*)&hib[u * 4];
            *(ushort4*)&vt2[bl + u * 4] = *(ushort4*)&lob[u * 4];
        }
    }
}

__global__ __launch_bounds__(256) void convert_sw(
    const float* __restrict__ Cpsw, const float* __restrict__ bl,
    float* __restrict__ swv)
{
    const int idx = blockIdx.x * 256 + threadIdx.x;   // < 294912
    swv[idx] = Cpsw[idx] + bl[idx % NSW_];
}

// ---------------------------------------------------------------------------
// sig16[h][b][l][t] = mask ? 0 : max(sigmoid(bias_h + w_h · ploc[b,l,t,:]), 1e-6)
// ---------------------------------------------------------------------------
__global__ __launch_bounds__(256) void sig_kernel(
    const float* __restrict__ ploc, const float* __restrict__ swv,
    const int* __restrict__ maskp, _Float16* __restrict__ sig16)
{
    const int b = blockIdx.y;
    const int l = blockIdx.x;
    const int tid = threadIdx.x;

    __shared__ float pls[512 * 5];
    __shared__ float sws[72];
    __shared__ int   msk[512];

    const float* src = ploc + (size_t)(b * 512 + l) * 512 * 5;
    for (int i = tid; i < 640; i += 256)
        *(float4*)&pls[i * 4] = *(const float4*)(src + i * 4);
    if (tid < 72) sws[tid] = swv[(size_t)(b * 512 + l) * NSW_ + tid];
    for (int i = tid; i < 512; i += 256) msk[i] = maskp[b * 512 + i];
    __syncthreads();

    for (int e = tid; e < H_ * 512; e += 256) {
        const int t  = e & 511;
        const int hh = e >> 9;
        float s = sws[hh * 6];
#pragma unroll
        for (int d = 0; d < SD_; d++) s += sws[hh * 6 + 1 + d] * pls[t * 5 + d];
        const float sig = msk[t] ? 0.f : fmaxf(1.f / (1.f + __expf(-s)), 1e-6f);
        sig16[(((size_t)hh * B_ + b) * 512 + l) * 512 + t] = (_Float16)sig;
    }
}

// ---------------------------------------------------------------------------
// MFMA attention. 1-D grid id = ltile*96 + hb so all 8 l-tiles of one (h,b)
// land on the same XCD (round-robin id%8) -> K/V slab shared in L2.
// Unnormalized p kept in 128 VGPRs across the full t-loop; row sums via
// shuffle+LDS; fused written normalized EXACTLY ONCE (no reread).
// ---------------------------------------------------------------------------
__global__ __launch_bounds__(256, 2) void attn_kernel(
    const ushort_t* __restrict__ qs2, const ushort_t* __restrict__ ks2,
    const ushort_t* __restrict__ vt2, const _Float16* __restrict__ sig16,
    float* __restrict__ fused, ushort_t* __restrict__ outp2)
{
    const int id = blockIdx.x;      // 0..767
    const int hb = id % 96;
    const int lt = id / 96;
    const int h  = hb >> 3;
    const int b  = hb & 7;
    const int l0 = lt << 6;
    const int tid  = threadIdx.x;
    const int lane = tid & 63;
    const int wv   = tid >> 6;
    const int l15  = lane & 15;
    const int quad = lane >> 4;

    __shared__ __align__(16) ushort_t qs[64 * 128];
    __shared__ __align__(16) ushort_t ks[64 * 128];
    __shared__ __align__(16) ushort_t vts[128 * 64];
    __shared__ __align__(16) ushort_t ps[64 * 136];   // [l][hi64 | lo64 | pad]
    __shared__ __align__(16) _Float16 ss[64 * 64];    // sig tile [l][t]
    __shared__ float ssb[4 * 64];
    __shared__ float ssum[64];

    // stage Q tile once (swizzled chunks)
    {
        const size_t qbase = ((size_t)hb * 512 + l0) * 128;
#pragma unroll
        for (int j = 0; j < 4; j++) {
            const int i = tid + 256 * j;
            const int r = i >> 4, c = i & 15, gc = c ^ (r & 7);
            gload_lds16(qs2 + qbase + r * 128 + gc * 8, &qs[i * 8]);
        }
    }

    f32x4 preg[8][4];   // unnormalized p, C-layout: [t-tile][mt][r2]
    f32x4 accpv[4] = {};

#pragma unroll
    for (int tt = 0; tt < 8; tt++) {
        const int t0 = tt << 6;
        __syncthreads();
        {
            const size_t kbase = ((size_t)hb * 512 + t0) * 128;
#pragma unroll
            for (int j = 0; j < 4; j++) {
                const int i = tid + 256 * j;
                const int r = i >> 4, c = i & 15, gc = c ^ (r & 7);
                gload_lds16(ks2 + kbase + r * 128 + gc * 8, &ks[i * 8]);
            }
            const size_t vbase = (size_t)hb * 128 * 512;
#pragma unroll
            for (int j = 0; j < 4; j++) {
                const int i = tid + 256 * j;
                const int r = i >> 3, c = i & 7, gc = c ^ (r & 7);
                gload_lds16(vt2 + vbase + (size_t)r * 512 + t0 + gc * 8, &vts[i * 8]);
            }
            // sig tile: 64 rows x 64 f16 = 8 KB = 512 x 16B chunks
            const _Float16* sgb = sig16 + ((size_t)hb * 512 + l0) * 512 + t0;
#pragma unroll
            for (int j = 0; j < 2; j++) {
                const int i = tid + 256 * j;
                const int r = i >> 3, c = i & 7;
                gload_lds16(sgb + (size_t)r * 512 + c * 8, &ss[i * 8]);
            }
        }
        __syncthreads();

        // ---- QK ----
        f32x4 acq[4] = {};
        {
            const int trow = wv * 16 + l15;
            const int tsw  = trow & 7;
            const bf16x8 bk0 = *(const bf16x8*)&ks[trow * 128 + ((0  + quad) ^ tsw) * 8];
            const bf16x8 bk1 = *(const bf16x8*)&ks[trow * 128 + ((4  + quad) ^ tsw) * 8];
            const bf16x8 bk2 = *(const bf16x8*)&ks[trow * 128 + ((8  + quad) ^ tsw) * 8];
            const bf16x8 bk3 = *(const bf16x8*)&ks[trow * 128 + ((12 + quad) ^ tsw) * 8];
#pragma unroll
            for (int mt = 0; mt < 4; mt++) {
                const int arow = mt * 16 + l15;
                const int asw  = arow & 7;
                const bf16x8 a0 = *(const bf16x8*)&qs[arow * 128 + ((0  + quad) ^ asw) * 8];
                const bf16x8 a1 = *(const bf16x8*)&qs[arow * 128 + ((4  + quad) ^ asw) * 8];
                const bf16x8 a2 = *(const bf16x8*)&qs[arow * 128 + ((8  + quad) ^ asw) * 8];
                const bf16x8 a3 = *(const bf16x8*)&qs[arow * 128 + ((12 + quad) ^ asw) * 8];
                f32x4 a = acq[mt];
                a = __builtin_amdgcn_mfma_f32_16x16x32_bf16(a0, bk0, a, 0, 0, 0);
                a = __builtin_amdgcn_mfma_f32_16x16x32_bf16(a1, bk1, a, 0, 0, 0);
                a = __builtin_amdgcn_mfma_f32_16x16x32_bf16(a0, bk2, a, 0, 0, 0);
                a = __builtin_amdgcn_mfma_f32_16x16x32_bf16(a1, bk3, a, 0, 0, 0);
                a = __builtin_amdgcn_mfma_f32_16x16x32_bf16(a2, bk0, a, 0, 0, 0);
                a = __builtin_amdgcn_mfma_f32_16x16x32_bf16(a3, bk1, a, 0, 0, 0);
                acq[mt] = a;
            }
        }

        // ---- p = sig * exp(qk/8): keep fp32 in regs, split hi/lo to LDS ----
        {
            const int tcol = wv * 16 + l15;
#pragma unroll
            for (int mt = 0; mt < 4; mt++)
#pragma unroll
                for (int r2 = 0; r2 < 4; r2++) {
                    const int lrow = mt * 16 + quad * 4 + r2;
                    const float sg = (float)ss[lrow * 64 + tcol];
                    const float p  = sg * __expf(acq[mt][r2] * 0.125f);
                    preg[tt][mt][r2] = p;
                    const ushort_t hi = f2bf(p);
                    const ushort_t lo = f2bf(p - bf2f(hi));
                    ps[lrow * 136 + tcol]      = hi;
                    ps[lrow * 136 + 64 + tcol] = lo;
                }
        }
        __syncthreads();

        // ---- PV ----
        {
            const int vrh = wv * 16 + l15;
            const int vrl = 64 + vrh;
            const int swh = vrh & 7, swl = vrl & 7;
            const bf16x8 bh0 = *(const bf16x8*)&vts[vrh * 64 + ((0 + quad) ^ swh) * 8];
            const bf16x8 bh1 = *(const bf16x8*)&vts[vrh * 64 + ((4 + quad) ^ swh) * 8];
            const bf16x8 bl0 = *(const bf16x8*)&vts[vrl * 64 + ((0 + quad) ^ swl) * 8];
            const bf16x8 bl1 = *(const bf16x8*)&vts[vrl * 64 + ((4 + quad) ^ swl) * 8];
#pragma unroll
            for (int mt = 0; mt < 4; mt++) {
                const int prow = mt * 16 + l15;
                const bf16x8 ph0 = *(const bf16x8*)&ps[prow * 136 + 0  + quad * 8];
                const bf16x8 ph1 = *(const bf16x8*)&ps[prow * 136 + 32 + quad * 8];
                const bf16x8 pl0 = *(const bf16x8*)&ps[prow * 136 + 64 + quad * 8];
                const bf16x8 pl1 = *(const bf16x8*)&ps[prow * 136 + 96 + quad * 8];
                f32x4 a = accpv[mt];
                a = __builtin_amdgcn_mfma_f32_16x16x32_bf16(ph0, bh0, a, 0, 0, 0);
                a = __builtin_amdgcn_mfma_f32_16x16x32_bf16(ph1, bh1, a, 0, 0, 0);
                a = __builtin_amdgcn_mfma_f32_16x16x32_bf16(ph0, bl0, a, 0, 0, 0);
                a = __builtin_amdgcn_mfma_f32_16x16x32_bf16(ph1, bl1, a, 0, 0, 0);
                a = __builtin_amdgcn_mfma_f32_16x16x32_bf16(pl0, bh0, a, 0, 0, 0);
                a = __builtin_amdgcn_mfma_f32_16x16x32_bf16(pl1, bh1, a, 0, 0, 0);
                accpv[mt] = a;
            }
        }
    }

    // ---- row sums: per-thread partial over 8 tiles, shuffle over 16 t-lanes,
    //      LDS combine over 4 waves ----
    float part[4][4];
#pragma unroll
    for (int mt = 0; mt < 4; mt++)
#pragma unroll
        for (int r2 = 0; r2 < 4; r2++) {
            float s = 0.f;
#pragma unroll
            for (int tt = 0; tt < 8; tt++) s += preg[tt][mt][r2];
#pragma unroll
            for (int off = 1; off < 16; off <<= 1)
                s += __shfl_xor(s, off, 64);
            part[mt][r2] = s;     // all lanes in a quad now hold the wave-sum
        }
    __syncthreads();
    if (l15 == 0) {
#pragma unroll
        for (int mt = 0; mt < 4; mt++)
#pragma unroll
            for (int r2 = 0; r2 < 4; r2++)
                ssb[wv * 64 + mt * 16 + quad * 4 + r2] = part[mt][r2];
    }
    __syncthreads();
    if (tid < 64)
        ssum[tid] = ssb[tid] + ssb[64 + tid] + ssb[128 + tid] + ssb[192 + tid];
    __syncthreads();

    float inv[4][4];
#pragma unroll
    for (int mt = 0; mt < 4; mt++)
#pragma unroll
        for (int r2 = 0; r2 < 4; r2++)
            inv[mt][r2] = 1.f / ssum[mt * 16 + quad * 4 + r2];

    // ---- normalized fused store (single pass) ----
    {
        float* fb = fused + ((size_t)hb * 512 + l0) * 512 + wv * 16 + l15;
#pragma unroll
        for (int tt = 0; tt < 8; tt++)
#pragma unroll
            for (int mt = 0; mt < 4; mt++)
#pragma unroll
                for (int r2 = 0; r2 < 4; r2++)
                    fb[(size_t)(mt * 16 + quad * 4 + r2) * 512 + tt * 64] =
                        preg[tt][mt][r2] * inv[mt][r2];
    }

    // ---- normalized PV output, split hi/lo for final GEMM ----
#pragma unroll
    for (int mt = 0; mt < 4; mt++)
#pragma unroll
        for (int r2 = 0; r2 < 4; r2++) {
            const int lrow = mt * 16 + quad * 4 + r2;
            const float val = accpv[mt][r2] * inv[mt][r2];
            const ushort_t hi = f2bf(val);
            const ushort_t lo = f2bf(val - bf2f(hi));
            const size_t obase = ((size_t)(b * 512 + l0 + lrow)) * K2_ + h * 64 + wv * 16 + l15;
            outp2[obase]       = hi;
            outp2[obase + D_]  = lo;
        }
}

// ---------------------------------------------------------------------------
extern "C" void kernel_launch(void* const* d_in, const int* in_sizes, int n_in,
                              void* d_out, int out_size, void* d_ws, size_t ws_size,
                              hipStream_t stream) {
    const float* q    = (const float*)d_in[0];
    const float* k    = (const float*)d_in[1];
    const float* v    = (const float*)d_in[2];
    const float* ploc = (const float*)d_in[3];
    const int*   mask = (const int*)  d_in[4];
    const float* Wq   = (const float*)d_in[5];
    const float* bq   = (const float*)d_in[6];
    const float* Wk   = (const float*)d_in[7];
    const float* bk   = (const float*)d_in[8];
    const float* Wv   = (const float*)d_in[9];
    const float* bv   = (const float*)d_in[10];
    const float* Wl   = (const float*)d_in[11];
    const float* bl   = (const float*)d_in[12];
    const float* Wf   = (const float*)d_in[13];
    const float* bf   = (const float*)d_in[14];

    char* base = (char*)d_ws;
    short*    q2    = (short*)(base + 0);             // 12,582,912
    short*    k2    = (short*)(base + 12582912);
    short*    v2    = (short*)(base + 25165824);
    short*    WqT3  = (short*)(base + 37748736);      //  3,538,944
    short*    WkT3  = (short*)(base + 41287680);
    short*    WvT3  = (short*)(base + 44826624);
    short*    WlT3  = (short*)(base + 48365568);      //    589,824
    short*    WfT3  = (short*)(base + 48955392);      //  3,538,944 (live -> final)
    float*    Cp    = (float*)(base + 52494336);      // 37,748,736 (3x 4096x768 f32)
    float*    Cpsw  = (float*)(base + 90243072);      //  1,179,648
    ushort_t* qs2a  = (ushort_t*)q2;                  // overlay (q2 dead after proj)
    ushort_t* ks2a  = (ushort_t*)k2;
    ushort_t* vt2   = (ushort_t*)v2;
    float*    swv   = (float*)WqT3;                   // overlay
    _Float16* sig16 = (_Float16*)(base + 52494336);   // 50,331,648 overlay over Cp+
    ushort_t* outp2 = (ushort_t*)(base + 102825984);  // 12,582,912 -> total 115,408,896

    float* out   = (float*)d_out;
    float* fused = out + (size_t)4096 * D_;

    zero_kernel<<<dim3(9504), 256, 0, stream>>>((float4*)Cp);   // Cp + Cpsw
    bias_init<<<dim3(3072), 256, 0, stream>>>((float4*)out, (const float4*)bf);

    asplit_kernel<<<dim3(3, 4096, 3), 256, 0, stream>>>(q, k, v, q2, k2, v2);
    wsplit_kernel<<<dim3(12, 12, 5), 256, 0, stream>>>(
        Wq, Wk, Wv, Wl, Wf, WqT3, WkT3, WvT3, WlT3, WfT3);

    proj_gemm<<<dim3(1216), 256, 0, stream>>>(
        q2, k2, v2, WqT3, WkT3, WvT3, WlT3, Cp, Cpsw);

    convert_qk<<<dim3(512, 1, 2), 256, 0, stream>>>(Cp, bq, bk, qs2a, ks2a);
    convert_v<<<dim3(8, 8, 12), 256, 0, stream>>>(Cp, bv, vt2);
    convert_sw<<<dim3(1152), 256, 0, stream>>>(Cpsw, bl, swv);

    sig_kernel<<<dim3(512, 8), 256, 0, stream>>>(ploc, swv, mask, sig16);

    attn_kernel<<<dim3(768), 256, 0, stream>>>(
        qs2a, ks2a, vt2, sig16, fused, outp2);

    final_gemm<<<dim3(768), 256, 0, stream>>>((const short*)outp2, WfT3, out);
}